// Round 3
// baseline (226.904 us; speedup 1.0000x reference)
//
#include <hip/hip_runtime.h>

#define SS 1024
#define GG 10
#define FF 5
#define BB 8
#define CC 3
#define KK (2 * FF + 1)

// ---------------------------------------------------------------------------
// Kernel 1: smooth the (B,1,G,G) offset grids with an 11x11 gaussian
// (edge-padded), scale by max_offset, clip, store field [B][2][G][G] in ws.
// ---------------------------------------------------------------------------
__global__ __launch_bounds__(256) void rds_smooth_kernel(
    const float* __restrict__ ox, const float* __restrict__ oy,
    const float* __restrict__ w, const void* __restrict__ max_move_p,
    float* __restrict__ gs)
{
    int idx = blockIdx.x * 256 + threadIdx.x;
    if (idx >= BB * 2 * GG * GG) return;
    int j  = idx % GG;
    int i  = (idx / GG) % GG;
    int ch = (idx / (GG * GG)) % 2;
    int b  = idx / (2 * GG * GG);

    const float* o = (ch == 0 ? ox : oy) + b * GG * GG;

    // max_move: python scalar; hedge int32 vs float32 storage
    int mi = *(const int*)max_move_p;
    float mv = (mi >= -100000 && mi <= 100000) ? (float)mi : __int_as_float(mi);
    float max_offset = 2.0f * mv / (float)SS;

    float acc = 0.0f;
    for (int u = 0; u < KK; ++u) {
        int yy = min(max(i + u - FF, 0), GG - 1);
        for (int v = 0; v < KK; ++v) {
            int xx = min(max(j + v - FF, 0), GG - 1);
            acc += o[yy * GG + xx] * w[u * KK + v];
        }
    }
    acc *= max_offset;
    acc = fminf(fmaxf(acc, -max_offset), max_offset);
    gs[idx] = acc;
}

// ---------------------------------------------------------------------------
// Kernel 2: 4-row x 256-col tile per block.
//
// R6/R7: the R5 counters showed VGPR_Count=36 — impossible to hold the 24
// declared f32x2 gather results (48 VGPRs), proving the compiler serialized
// the gathers to ~2-4 in flight (the R3/R4 register-starvation, un-fixed by
// arrays+sched_barrier). Wave-lifetime arithmetic: 128 waves/CU * 28K cycles
// = pure latency serialization; kernel at 2.0 TB/s (32% of achievable), so
// not BW-bound. Fix: compiler-proof MLP via volatile inline-asm
// global_load_dword (SGPR base + VGPR byte offset, dword-aligned; the x0/x1
// horizontal pair via offset:0 / offset:4 imm). All 48 loads issue before a
// single s_waitcnt vmcnt(0) + sched_barrier(0) (rule #18 fence). 48-deep MLP
// per wave * ~16 waves/CU amortizes the ~600-900cy gather latency.
//
// Keeps: R5 XCD-chunked swizzle, float2-pair weight remap (d = x0-clamp),
// nontemporal coalesced stores.
// ---------------------------------------------------------------------------
__global__ __launch_bounds__(256, 4) void rds_deform_kernel(
    const float* __restrict__ x, const float* __restrict__ gs,
    float* __restrict__ out)
{
    int h     = blockIdx.x;          // hardware id: h % 8 ~ XCD
    int wg    = ((h & 7) << 10) | (h >> 3);   // work id, contiguous per XCD
    int xseg  = wg & 3;
    int ytile = (wg >> 2) & 255;     // SS/4 = 256 tiles
    int b     = wg >> 10;
    int tid   = threadIdx.x;
    int ybase = ytile << 2;
    int xc    = (xseg << 8) + tid;

    __shared__ float rowf[4][2][GG];

    const float GdS = (float)GG / (float)SS;

    // Fill 4 rows x 2 channels x 10 cols of y-interpolated field
    if (tid < 80) {
        int p  = tid / 20;
        int r  = tid - p * 20;
        int ch = r / GG;
        int j  = r - ch * GG;
        int y  = ybase + p;
        float sy  = fmaxf(((float)y + 0.5f) * GdS - 0.5f, 0.0f);
        int   i0y = min((int)sy, GG - 1);
        int   i1y = min(i0y + 1, GG - 1);
        float wyu = sy - (float)i0y;
        const float* gb = gs + (b * 2 + ch) * GG * GG;
        rowf[p][ch][j] = gb[i0y * GG + j] + wyu * (gb[i1y * GG + j] - gb[i0y * GG + j]);
    }
    __syncthreads();

    // ---- x-direction quantities: once per thread ----
    float sx  = fmaxf(((float)xc + 0.5f) * GdS - 0.5f, 0.0f);
    int   i0x = min((int)sx, GG - 1);
    int   i1x = min(i0x + 1, GG - 1);
    float wxu = sx - (float)i0x;
    float pxc = (float)xc * (2.0f / (float)(SS - 1)) - 1.0f;

    unsigned boa[4], bob[4];     // BYTE offsets of float2 base, rows cy0/cy1
    float wxa[4], wxb[4];        // horizontal weights for the two dwords
    float wya[4], wyb[4];        // vertical weights incl. row masks

    #pragma unroll
    for (int p = 0; p < 4; ++p) {
        float r0a = rowf[p][0][i0x], r0b = rowf[p][0][i1x];
        float r1a = rowf[p][1][i0x], r1b = rowf[p][1][i1x];
        float gxv = r0a + wxu * (r0b - r0a);
        float gyv = r1a + wxu * (r1b - r1a);

        float py  = (float)(ybase + p) * (2.0f / (float)(SS - 1)) - 1.0f;
        float gr0 = fminf(fmaxf(gxv + pxc, -1.0f), 1.0f);
        float gr1 = fminf(fmaxf(gyv + py,  -1.0f), 1.0f);

        // ((gr+1)*S-1)/2 == gr*512 + 511.5
        float ix = gr0 * 512.0f + 511.5f;
        float iy = gr1 * 512.0f + 511.5f;

        int   x0 = (int)floorf(ix);      // in [-1, SS-1] after clip
        int   y0 = (int)floorf(iy);
        int   y1 = y0 + 1;
        float wx = ix - (float)x0;
        float wy = iy - (float)y0;

        // horizontal: one aligned pair at base=clamp(x0,0,S-2); d in {-1,0,1}
        int base = min(max(x0, 0), SS - 2);
        int d    = x0 - base;
        // d==0 : (1-wx)*lo + wx*hi   (both corners in range)
        // d==-1: x0=-1 -> corner x1=0 is lo  -> wx*lo
        // d==+1: x0=SS-1 -> corner x0 is hi  -> (1-wx)*hi
        wxa[p] = (d == 0) ? (1.0f - wx) : ((d < 0) ? wx : 0.0f);
        wxb[p] = (d == 0) ? wx          : ((d < 0) ? 0.0f : (1.0f - wx));

        float my0 = ((unsigned)y0 < (unsigned)SS) ? 1.0f : 0.0f;
        float my1 = ((unsigned)y1 < (unsigned)SS) ? 1.0f : 0.0f;
        wya[p] = (1.0f - wy) * my0;
        wyb[p] = wy * my1;

        int cy0 = min(max(y0, 0), SS - 1);
        int cy1 = min(max(y1, 0), SS - 1);
        boa[p] = (unsigned)((cy0 * SS + base) * 4);
        bob[p] = (unsigned)((cy1 * SS + base) * 4);
    }

    const float* xb = x + (size_t)b * CC * SS * SS;

    // ---- issue ALL 48 gathers via volatile asm: compiler cannot serialize.
    // saddr form: addr = SGPR64(base) + VGPR32(byte off) + imm. All offsets
    // are dword-aligned and < 4 MB.
    float lax[CC * 4], lay[CC * 4], lbx[CC * 4], lby[CC * 4];
    {
        const float* ib = xb;
        #pragma unroll
        for (int c = 0; c < CC; ++c) {
            #pragma unroll
            for (int p = 0; p < 4; ++p) {
                int k = c * 4 + p;
                asm volatile("global_load_dword %0, %1, %2"
                             : "=v"(lax[k]) : "v"(boa[p]), "s"(ib));
                asm volatile("global_load_dword %0, %1, %2 offset:4"
                             : "=v"(lay[k]) : "v"(boa[p]), "s"(ib));
                asm volatile("global_load_dword %0, %1, %2"
                             : "=v"(lbx[k]) : "v"(bob[p]), "s"(ib));
                asm volatile("global_load_dword %0, %1, %2 offset:4"
                             : "=v"(lby[k]) : "v"(bob[p]), "s"(ib));
            }
            ib += SS * SS;
        }
    }
    // Compiler doesn't track vmcnt for asm loads: explicit drain + scheduling
    // fence so no consumer is hoisted above data arrival (rule #18).
    asm volatile("s_waitcnt vmcnt(0)" ::: "memory");
    __builtin_amdgcn_sched_barrier(0);

    // ---- FMAs + coalesced nontemporal stores ----
    size_t obase = (((size_t)b * CC) * SS + ybase) * SS + xc;
    #pragma unroll
    for (int c = 0; c < CC; ++c) {
        #pragma unroll
        for (int p = 0; p < 4; ++p) {
            int k = c * 4 + p;
            float v = wya[p] * (lax[k] * wxa[p] + lay[k] * wxb[p])
                    + wyb[p] * (lbx[k] * wxa[p] + lby[k] * wxb[p]);
            __builtin_nontemporal_store(
                v, out + obase + (size_t)c * SS * SS + (size_t)(p * SS));
        }
    }
}

extern "C" void kernel_launch(void* const* d_in, const int* in_sizes, int n_in,
                              void* d_out, int out_size, void* d_ws, size_t ws_size,
                              hipStream_t stream) {
    const float* x        = (const float*)d_in[0];
    const float* offset_x = (const float*)d_in[1];
    const float* offset_y = (const float*)d_in[2];
    const float* weight   = (const float*)d_in[3];
    const void*  max_move = d_in[4];
    float* out = (float*)d_out;
    float* gs  = (float*)d_ws;   // [B][2][G][G] smoothed, scaled, clipped field

    int n1 = BB * 2 * GG * GG;   // 1600
    rds_smooth_kernel<<<(n1 + 255) / 256, 256, 0, stream>>>(
        offset_x, offset_y, weight, max_move, gs);

    int nblocks = BB * (SS / 4) * 4;   // 8192: (b, ytile, xseg)
    rds_deform_kernel<<<nblocks, 256, 0, stream>>>(x, gs, out);
}

// Round 10
// 194.004 us; speedup vs baseline: 1.1696x; 1.1696x over previous
//
#include <hip/hip_runtime.h>

#define SS 1024
#define GG 10
#define FF 5
#define BB 8
#define CC 3
#define KK (2 * FF + 1)

typedef float f32x2 __attribute__((ext_vector_type(2), aligned(4)));

// ---------------------------------------------------------------------------
// Kernel 1: smooth the (B,1,G,G) offset grids with an 11x11 gaussian
// (edge-padded), scale by max_offset, clip, store field [B][2][G][G] in ws.
// ---------------------------------------------------------------------------
__global__ __launch_bounds__(256) void rds_smooth_kernel(
    const float* __restrict__ ox, const float* __restrict__ oy,
    const float* __restrict__ w, const void* __restrict__ max_move_p,
    float* __restrict__ gs)
{
    int idx = blockIdx.x * 256 + threadIdx.x;
    if (idx >= BB * 2 * GG * GG) return;
    int j  = idx % GG;
    int i  = (idx / GG) % GG;
    int ch = (idx / (GG * GG)) % 2;
    int b  = idx / (2 * GG * GG);

    const float* o = (ch == 0 ? ox : oy) + b * GG * GG;

    // max_move: python scalar; hedge int32 vs float32 storage
    int mi = *(const int*)max_move_p;
    float mv = (mi >= -100000 && mi <= 100000) ? (float)mi : __int_as_float(mi);
    float max_offset = 2.0f * mv / (float)SS;

    float acc = 0.0f;
    for (int u = 0; u < KK; ++u) {
        int yy = min(max(i + u - FF, 0), GG - 1);
        for (int v = 0; v < KK; ++v) {
            int xx = min(max(j + v - FF, 0), GG - 1);
            acc += o[yy * GG + xx] * w[u * KK + v];
        }
    }
    acc *= max_offset;
    acc = fminf(fmaxf(acc, -max_offset), max_offset);
    gs[idx] = acc;
}

// ---------------------------------------------------------------------------
// Kernel 2: 4-row x 256-col tile per block.
//
// R9 ledger re-read: R0->R1 was a single-variable A/B on the XCD swizzle:
// 201.2 -> 212.7 us end-to-end. Calibrating fixed harness overhead from the
// two measured rounds (R1: 212.7/75.2, R3: 226.9/90.9 => total ~ deform+137)
// gives baseline deform ~64 us WITHOUT swizzle vs 75 WITH. The swizzle cut
// FETCH (77->48 MB) but cost +17% time: not BW-bound, and the h&7->XCD
// locality assumption evidently wrong for this dispatch. REVERTED.
//
// R8 theory (still the live hypothesis): R6 proved forcing MLP fails (RA
// targets 8 waves/EU, spills the 48-reg batch -> 90us at VGPR=36).
// Occupancy-level MLP already covers latency; the ~50 cy/gather observed is
// TA/L1 address-processing throughput on divergent 64-lane gathers. Lever:
// fewer gathers / fewer active lanes.
//
// Row-sharing: iy(p+1) ~= iy(p) + 1.0009, so row p's bottom pair (ob[p]) is
// byte-identical to row p+1's top pair (oa[p+1]) for ~90% of lanes. Load
// la[0..3] + lb[3] unconditionally (5 gathers/ch), and for p<3 issue the
// fixup gather only for mismatching lanes under exec mask (TA cost scales
// with active lanes; mismatches are sparse). 24 -> ~16 effective gathers.
//
// Keeps: float2-pair weight remap (d = x0-clamp), nontemporal coalesced
// stores, compiler-scheduled loads (asm reverted).
// ---------------------------------------------------------------------------
__global__ __launch_bounds__(256, 4) void rds_deform_kernel(
    const float* __restrict__ x, const float* __restrict__ gs,
    float* __restrict__ out)
{
    int wg    = blockIdx.x;          // R9: identity mapping (swizzle reverted)
    int xseg  = wg & 3;
    int ytile = (wg >> 2) & 255;     // SS/4 = 256 tiles
    int b     = wg >> 10;
    int tid   = threadIdx.x;
    int ybase = ytile << 2;
    int xc    = (xseg << 8) + tid;

    __shared__ float rowf[4][2][GG];

    const float GdS = (float)GG / (float)SS;

    // Fill 4 rows x 2 channels x 10 cols of y-interpolated field
    if (tid < 80) {
        int p  = tid / 20;
        int r  = tid - p * 20;
        int ch = r / GG;
        int j  = r - ch * GG;
        int y  = ybase + p;
        float sy  = fmaxf(((float)y + 0.5f) * GdS - 0.5f, 0.0f);
        int   i0y = min((int)sy, GG - 1);
        int   i1y = min(i0y + 1, GG - 1);
        float wyu = sy - (float)i0y;
        const float* gb = gs + (b * 2 + ch) * GG * GG;
        rowf[p][ch][j] = gb[i0y * GG + j] + wyu * (gb[i1y * GG + j] - gb[i0y * GG + j]);
    }
    __syncthreads();

    // ---- x-direction quantities: once per thread ----
    float sx  = fmaxf(((float)xc + 0.5f) * GdS - 0.5f, 0.0f);
    int   i0x = min((int)sx, GG - 1);
    int   i1x = min(i0x + 1, GG - 1);
    float wxu = sx - (float)i0x;
    float pxc = (float)xc * (2.0f / (float)(SS - 1)) - 1.0f;

    int   oa[4], ob[4];          // float2 base offsets, rows cy0 / cy1
    float wxa[4], wxb[4];        // horizontal weights for f2.x / f2.y
    float wya[4], wyb[4];        // vertical weights incl. row masks

    #pragma unroll
    for (int p = 0; p < 4; ++p) {
        float r0a = rowf[p][0][i0x], r0b = rowf[p][0][i1x];
        float r1a = rowf[p][1][i0x], r1b = rowf[p][1][i1x];
        float gxv = r0a + wxu * (r0b - r0a);
        float gyv = r1a + wxu * (r1b - r1a);

        float py  = (float)(ybase + p) * (2.0f / (float)(SS - 1)) - 1.0f;
        float gr0 = fminf(fmaxf(gxv + pxc, -1.0f), 1.0f);
        float gr1 = fminf(fmaxf(gyv + py,  -1.0f), 1.0f);

        // ((gr+1)*S-1)/2 == gr*512 + 511.5
        float ix = gr0 * 512.0f + 511.5f;
        float iy = gr1 * 512.0f + 511.5f;

        int   x0 = (int)floorf(ix);      // in [-1, SS-1] after clip
        int   y0 = (int)floorf(iy);
        int   y1 = y0 + 1;
        float wx = ix - (float)x0;
        float wy = iy - (float)y0;

        // horizontal: one float2 load at base=clamp(x0,0,S-2); d in {-1,0,1}
        int base = min(max(x0, 0), SS - 2);
        int d    = x0 - base;
        // d==0 : (1-wx)*f.x + wx*f.y   (both corners in range)
        // d==-1: x0=-1 -> corner x1=0 is f.x  -> wx*f.x
        // d==+1: x0=SS-1 -> corner x0 is f.y  -> (1-wx)*f.y
        wxa[p] = (d == 0) ? (1.0f - wx) : ((d < 0) ? wx : 0.0f);
        wxb[p] = (d == 0) ? wx          : ((d < 0) ? 0.0f : (1.0f - wx));

        float my0 = ((unsigned)y0 < (unsigned)SS) ? 1.0f : 0.0f;
        float my1 = ((unsigned)y1 < (unsigned)SS) ? 1.0f : 0.0f;
        wya[p] = (1.0f - wy) * my0;
        wyb[p] = wy * my1;

        int cy0 = min(max(y0, 0), SS - 1);
        int cy1 = min(max(y1, 0), SS - 1);
        oa[p] = cy0 * SS + base;
        ob[p] = cy1 * SS + base;
    }

    const float* xb = x + (size_t)b * CC * SS * SS;
    size_t obase = (((size_t)b * CC) * SS + ybase) * SS + xc;

    #pragma unroll
    for (int c = 0; c < CC; ++c) {
        const float* img = xb + (size_t)c * SS * SS;

        // 5 unconditional gathers: the 4 top-row pairs + the last bottom pair
        f32x2 la0 = *(const f32x2*)(img + oa[0]);
        f32x2 la1 = *(const f32x2*)(img + oa[1]);
        f32x2 la2 = *(const f32x2*)(img + oa[2]);
        f32x2 la3 = *(const f32x2*)(img + oa[3]);
        f32x2 lb3 = *(const f32x2*)(img + ob[3]);

        // bottom pair of row p == top pair of row p+1 for ~90% of lanes;
        // fixup gather only where the byte offsets differ (exec-masked).
        f32x2 lb0 = la1, lb1 = la2, lb2 = la3;
        if (ob[0] != oa[1]) lb0 = *(const f32x2*)(img + ob[0]);
        if (ob[1] != oa[2]) lb1 = *(const f32x2*)(img + ob[1]);
        if (ob[2] != oa[3]) lb2 = *(const f32x2*)(img + ob[2]);

        f32x2 la[4] = { la0, la1, la2, la3 };
        f32x2 lb[4] = { lb0, lb1, lb2, lb3 };

        #pragma unroll
        for (int p = 0; p < 4; ++p) {
            f32x2 fa = la[p];
            f32x2 fb = lb[p];
            float v = wya[p] * (fa.x * wxa[p] + fa.y * wxb[p])
                    + wyb[p] * (fb.x * wxa[p] + fb.y * wxb[p]);
            __builtin_nontemporal_store(
                v, out + obase + (size_t)c * SS * SS + (size_t)(p * SS));
        }
    }
}

extern "C" void kernel_launch(void* const* d_in, const int* in_sizes, int n_in,
                              void* d_out, int out_size, void* d_ws, size_t ws_size,
                              hipStream_t stream) {
    const float* x        = (const float*)d_in[0];
    const float* offset_x = (const float*)d_in[1];
    const float* offset_y = (const float*)d_in[2];
    const float* weight   = (const float*)d_in[3];
    const void*  max_move = d_in[4];
    float* out = (float*)d_out;
    float* gs  = (float*)d_ws;   // [B][2][G][G] smoothed, scaled, clipped field

    int n1 = BB * 2 * GG * GG;   // 1600
    rds_smooth_kernel<<<(n1 + 255) / 256, 256, 0, stream>>>(
        offset_x, offset_y, weight, max_move, gs);

    int nblocks = BB * (SS / 4) * 4;   // 8192: (b, ytile, xseg)
    rds_deform_kernel<<<nblocks, 256, 0, stream>>>(x, gs, out);
}